// Round 1
// baseline (619.950 us; speedup 1.0000x reference)
//
#include <hip/hip_runtime.h>
#include <hip/hip_bf16.h>

typedef __bf16 bf16_t;
typedef bf16_t bf16x8 __attribute__((ext_vector_type(8)));
typedef bf16_t bf16x4 __attribute__((ext_vector_type(4)));
typedef float f32x4 __attribute__((ext_vector_type(4)));

#define DIN 1024
#define DH 1024
#define DMOE 4096
#define NEXP 8
#define NTOK 4096

__device__ __forceinline__ void gload_lds16(const bf16_t* g, bf16_t* l) {
  __builtin_amdgcn_global_load_lds(
      (const __attribute__((address_space(1))) void*)g,
      (__attribute__((address_space(3))) void*)l, 16, 0, 0);
}

// ---------------- small utility kernels ----------------

__global__ void k_zero8(int* p) {
  if (threadIdx.x < 8) p[threadIdx.x] = 0;
}

// src [b][R][C] f32 -> dst [b][C][R] bf16
__global__ void k_transpose_cvt(const float* __restrict__ src, bf16_t* __restrict__ dst,
                                int R, int C) {
  __shared__ float tile[32][33];
  const size_t mofs = (size_t)blockIdx.z * R * C;
  const float* s = src + mofs;
  bf16_t* d = dst + mofs;
  const int c0 = blockIdx.x * 32, r0 = blockIdx.y * 32;
  const int tx = threadIdx.x, ty = threadIdx.y;
#pragma unroll
  for (int i = 0; i < 32; i += 8)
    tile[ty + i][tx] = s[(size_t)(r0 + ty + i) * C + (c0 + tx)];
  __syncthreads();
#pragma unroll
  for (int i = 0; i < 32; i += 8)
    d[(size_t)(c0 + ty + i) * R + (r0 + tx)] = (bf16_t)tile[tx][ty + i];
}

__global__ void k_cvt_bf16(const float* __restrict__ src, bf16_t* __restrict__ dst, int n4) {
  const int i = blockIdx.x * blockDim.x + threadIdx.x;
  if (i < n4) {
    const float4 v = *(const float4*)(src + (size_t)i * 4);
    bf16x4 o;
    o.x = (bf16_t)v.x; o.y = (bf16_t)v.y; o.z = (bf16_t)v.z; o.w = (bf16_t)v.w;
    *(bf16x4*)(dst + (size_t)i * 4) = o;
  }
}

// G[d][e] = sum_k W_in[d][k] * W_gate[k][e]  (fp64); row d==DH computes c[e] from b_in
__global__ void k_gate_prep(const float* __restrict__ Win, const float* __restrict__ Wgate,
                            const float* __restrict__ b_in, const float* __restrict__ b_gate,
                            double* __restrict__ G, double* __restrict__ cvec) {
  const int lane = threadIdx.x & 63;
  const int wave = (blockIdx.x * blockDim.x + threadIdx.x) >> 6;
  const int nw = (gridDim.x * blockDim.x) >> 6;
  for (int d = wave; d <= DIN; d += nw) {
    const float* row = (d < DIN) ? (Win + (size_t)d * DH) : b_in;
    double acc[8] = {0, 0, 0, 0, 0, 0, 0, 0};
    for (int k = lane; k < DH; k += 64) {
      const double xv = (double)row[k];
      const float* g = Wgate + (size_t)k * NEXP;
#pragma unroll
      for (int ee = 0; ee < 8; ++ee) acc[ee] += xv * (double)g[ee];
    }
#pragma unroll
    for (int ee = 0; ee < 8; ++ee) {
      double a = acc[ee];
      for (int o = 32; o > 0; o >>= 1) a += __shfl_down(a, o);
      acc[ee] = a;
    }
    if (lane == 0) {
      if (d < DIN) {
#pragma unroll
        for (int ee = 0; ee < 8; ++ee) G[(size_t)d * 8 + ee] = acc[ee];
      } else {
#pragma unroll
        for (int ee = 0; ee < 8; ++ee) cvec[ee] = acc[ee] + (double)b_gate[ee];
      }
    }
  }
}

// per token: fp64 logits via fused G, softmax, top-2, scatter into expert lists
__global__ void k_gating(const float* __restrict__ x, const double* __restrict__ G,
                         const double* __restrict__ cvec, int* __restrict__ cnt,
                         int* __restrict__ list, float* __restrict__ wlist) {
  const int lane = threadIdx.x & 63;
  const int t = blockIdx.x * (blockDim.x >> 6) + (threadIdx.x >> 6);
  if (t >= NTOK) return;
  const float* xr = x + (size_t)t * DIN;
  double acc[8] = {0, 0, 0, 0, 0, 0, 0, 0};
  for (int d = lane; d < DIN; d += 64) {
    const double xv = (double)xr[d];
    const double* g = G + (size_t)d * 8;
#pragma unroll
    for (int ee = 0; ee < 8; ++ee) acc[ee] += xv * g[ee];
  }
#pragma unroll
  for (int ee = 0; ee < 8; ++ee) {
    double a = acc[ee];
    for (int o = 32; o > 0; o >>= 1) a += __shfl_down(a, o);
    acc[ee] = a;
  }
  if (lane == 0) {
    double l[8];
#pragma unroll
    for (int ee = 0; ee < 8; ++ee) l[ee] = acc[ee] + cvec[ee];
    double m = l[0];
#pragma unroll
    for (int ee = 1; ee < 8; ++ee) m = fmax(m, l[ee]);
    double p[8];
#pragma unroll
    for (int ee = 0; ee < 8; ++ee) p[ee] = exp(l[ee] - m);
    int i1 = 0;
#pragma unroll
    for (int ee = 1; ee < 8; ++ee)
      if (p[ee] > p[i1]) i1 = ee;
    int i2 = (i1 == 0) ? 1 : 0;
#pragma unroll
    for (int ee = 0; ee < 8; ++ee)
      if (ee != i1 && p[ee] > p[i2]) i2 = ee;
    const double s2 = p[i1] + p[i2];
    const float w1 = (float)(p[i1] / s2);
    const float w2 = (float)(p[i2] / s2);
    int lp = atomicAdd(&cnt[i1], 1);
    list[i1 * NTOK + lp] = t * 2;
    wlist[i1 * NTOK + lp] = w1;
    lp = atomicAdd(&cnt[i2], 1);
    list[i2 * NTOK + lp] = t * 2 + 1;
    wlist[i2 * NTOK + lp] = w2;
  }
}

__global__ void k_scan(const int* __restrict__ cnt, int* __restrict__ offs) {
  if (threadIdx.x == 0) {
    int s = 0;
    for (int e = 0; e < NEXP; ++e) { offs[e] = s; s += cnt[e]; }
    offs[NEXP] = s;
  }
}

// moe_bf16[t] = bf16(eout[t][0] + eout[t][1])   (route weights already applied)
__global__ void k_combine(const float* __restrict__ eout, bf16_t* __restrict__ moebf) {
  const int i = blockIdx.x * blockDim.x + threadIdx.x;
  const int t = i >> 8;
  const int q = (i & 255) * 4;
  const float4 a = *(const float4*)(eout + ((size_t)t * 2) * DH + q);
  const float4 b = *(const float4*)(eout + ((size_t)t * 2 + 1) * DH + q);
  bf16x4 o;
  o.x = (bf16_t)(a.x + b.x); o.y = (bf16_t)(a.y + b.y);
  o.z = (bf16_t)(a.z + b.z); o.w = (bf16_t)(a.w + b.w);
  *(bf16x4*)(moebf + (size_t)t * DH + q) = o;
}

// ---------------- 128x128 BK=32 bf16 MFMA GEMM, 4 waves (m97 structure) ----------------
// C = A[M][K] * Bt[N][K]^T + bias, with mode-specific row gather / epilogue.
// MODE 0: plain, bf16 out (h)
// MODE 1: expert, A rows gathered via list (token = entry>>1), relu, bf16 out at rowOff+r
// MODE 2: expert, A = mid + rowOff, out fp32 scattered to eout[entry][*] scaled by wlist
// MODE 3: plain, fp32 out (final)
template <int MODE>
__global__ __launch_bounds__(256, 2) void k_gemm(
    const bf16_t* __restrict__ Abase, const bf16_t* __restrict__ Bbase,
    const float* __restrict__ biasBase, void* __restrict__ Cbase,
    int M, int N, int K,
    const int* __restrict__ cnt, const int* __restrict__ offs,
    const int* __restrict__ listBase, const float* __restrict__ wlistBase) {
  const int e = blockIdx.z;
  const int mblk = blockIdx.y, nblk = blockIdx.x;
  int Mloc = M;
  const bf16_t* A = Abase;
  const bf16_t* B = Bbase;
  const float* bias = biasBase;
  const int* myList = nullptr;
  const float* myW = nullptr;
  int rowOff = 0;
  if constexpr (MODE == 1 || MODE == 2) {
    Mloc = cnt[e];
    if (mblk * 128 >= Mloc) return;  // uniform early exit, before any barrier
    B = Bbase + (size_t)e * N * K;
    bias = biasBase + (size_t)e * N;
    myList = listBase + e * NTOK;
    myW = wlistBase + e * NTOK;
    rowOff = offs[e];
    if constexpr (MODE == 2) A = Abase + (size_t)rowOff * K;
  }

  __shared__ bf16_t As[128 * 32];
  __shared__ bf16_t Bs[128 * 32];

  const int tid = threadIdx.x;
  const int lane = tid & 63;
  const int wid = tid >> 6;
  const int wr = wid >> 1, wc = wid & 1;

  // staging: each wave stages rows [wid*32, wid*32+32) of A and of Bt, 16B/lane
  const int srow0 = wid * 32 + (lane >> 2);
  const int srow1 = srow0 + 16;
  const int skcol = (lane & 3) * 8;

  int ar0 = mblk * 128 + srow0;
  int ar1 = mblk * 128 + srow1;
  if constexpr (MODE == 1 || MODE == 2) {
    if (ar0 > Mloc - 1) ar0 = Mloc - 1;
    if (ar1 > Mloc - 1) ar1 = Mloc - 1;
  }
  size_t arow0 = (size_t)ar0, arow1 = (size_t)ar1;
  if constexpr (MODE == 1) {
    arow0 = (size_t)(myList[ar0] >> 1);
    arow1 = (size_t)(myList[ar1] >> 1);
  }
  const bf16_t* aptr0 = A + arow0 * K + skcol;
  const bf16_t* aptr1 = A + arow1 * K + skcol;
  const bf16_t* bptr0 = B + (size_t)(nblk * 128 + srow0) * K + skcol;
  const bf16_t* bptr1 = B + (size_t)(nblk * 128 + srow1) * K + skcol;

  bf16_t* asd0 = &As[(wid * 32) * 32];        // wave-uniform LDS bases
  bf16_t* asd1 = &As[(wid * 32 + 16) * 32];
  bf16_t* bsd0 = &Bs[(wid * 32) * 32];
  bf16_t* bsd1 = &Bs[(wid * 32 + 16) * 32];

  f32x4 acc[4][4] = {};

  const int nkt = K >> 5;
  for (int kt = 0; kt < nkt; ++kt) {
    __syncthreads();
    gload_lds16(aptr0, asd0);
    gload_lds16(aptr1, asd1);
    gload_lds16(bptr0, bsd0);
    gload_lds16(bptr1, bsd1);
    aptr0 += 32; aptr1 += 32; bptr0 += 32; bptr1 += 32;
    __syncthreads();  // drains vmcnt before barrier -> LDS tiles visible

    const int fr = lane & 15;
    const int kq = (lane >> 4) * 8;
    bf16x8 af[4], bfr[4];
#pragma unroll
    for (int m = 0; m < 4; ++m)
      af[m] = *(const bf16x8*)&As[(wr * 64 + m * 16 + fr) * 32 + kq];
#pragma unroll
    for (int n = 0; n < 4; ++n)
      bfr[n] = *(const bf16x8*)&Bs[(wc * 64 + n * 16 + fr) * 32 + kq];
#pragma unroll
    for (int m = 0; m < 4; ++m)
#pragma unroll
      for (int n = 0; n < 4; ++n)
        acc[m][n] = __builtin_amdgcn_mfma_f32_16x16x32_bf16(af[m], bfr[n], acc[m][n], 0, 0, 0);
  }

  // epilogue: C row = (lane>>4)*4 + j (+16m), col = lane&15 (+16n)  [m89-verified]
  const int colBase = nblk * 128 + wc * 64 + (lane & 15);
  const int rowBase = mblk * 128 + wr * 64 + ((lane >> 4) << 2);
#pragma unroll
  for (int n = 0; n < 4; ++n) {
    const int c = colBase + n * 16;
    const float bv = bias[c];
#pragma unroll
    for (int m = 0; m < 4; ++m) {
#pragma unroll
      for (int j = 0; j < 4; ++j) {
        const int r = rowBase + m * 16 + j;
        float v = acc[m][n][j] + bv;
        if constexpr (MODE == 0) {
          ((bf16_t*)Cbase)[(size_t)r * N + c] = (bf16_t)v;
        } else if constexpr (MODE == 1) {
          if (r < Mloc) {
            v = fmaxf(v, 0.0f);
            ((bf16_t*)Cbase)[(size_t)(rowOff + r) * N + c] = (bf16_t)v;
          }
        } else if constexpr (MODE == 2) {
          if (r < Mloc) {
            const int entry = myList[r];
            const float w = myW[r];
            ((float*)Cbase)[(size_t)entry * DH + c] = v * w;
          }
        } else {
          ((float*)Cbase)[(size_t)r * N + c] = v;
        }
      }
    }
  }
}

// ---------------- launch ----------------

extern "C" void kernel_launch(void* const* d_in, const int* in_sizes, int n_in,
                              void* d_out, int out_size, void* d_ws, size_t ws_size,
                              hipStream_t stream) {
  const float* x      = (const float*)d_in[0];
  const float* W_in   = (const float*)d_in[1];
  const float* b_in   = (const float*)d_in[2];
  const float* W_gate = (const float*)d_in[3];
  const float* b_gate = (const float*)d_in[4];
  const float* W1     = (const float*)d_in[5];
  const float* b1     = (const float*)d_in[6];
  const float* W2     = (const float*)d_in[7];
  const float* b2     = (const float*)d_in[8];
  const float* W_out  = (const float*)d_in[9];
  const float* b_out  = (const float*)d_in[10];

  char* ws = (char*)d_ws;
  size_t off = 0;
  auto alloc = [&](size_t bytes) -> void* {
    void* p = ws + off;
    off += (bytes + 255) & ~(size_t)255;
    return p;
  };

  bf16_t* WtIn  = (bf16_t*)alloc((size_t)DH * DIN * 2);          // [DH][DIN]
  bf16_t* Wt1   = (bf16_t*)alloc((size_t)NEXP * DMOE * DH * 2);  // [E][DMOE][DH]
  bf16_t* Wt2   = (bf16_t*)alloc((size_t)NEXP * DH * DMOE * 2);  // [E][DH][DMOE]
  bf16_t* WtOut = (bf16_t*)alloc((size_t)DH * DH * 2);           // [DOUT][DH]
  bf16_t* xbf   = (bf16_t*)alloc((size_t)NTOK * DIN * 2);
  bf16_t* hbf   = (bf16_t*)alloc((size_t)NTOK * DH * 2);
  bf16_t* mid   = (bf16_t*)alloc((size_t)2 * NTOK * DMOE * 2);   // [2N][DMOE]
  float*  eout  = (float*)alloc((size_t)2 * NTOK * DH * 4);      // [2N][DH] (t*2+slot)
  bf16_t* moebf = (bf16_t*)alloc((size_t)NTOK * DH * 2);
  double* G     = (double*)alloc((size_t)DIN * 8 * 8);
  double* cvec  = (double*)alloc(8 * 8);
  int*    cnt   = (int*)alloc(NEXP * 4);
  int*    offs  = (int*)alloc((NEXP + 1) * 4);
  int*    list  = (int*)alloc((size_t)NEXP * NTOK * 4);
  float*  wlist = (float*)alloc((size_t)NEXP * NTOK * 4);

  k_zero8<<<1, 64, 0, stream>>>(cnt);

  dim3 tb(32, 8, 1);
  k_transpose_cvt<<<dim3(DH / 32, DIN / 32, 1), tb, 0, stream>>>(W_in, WtIn, DIN, DH);
  k_transpose_cvt<<<dim3(DMOE / 32, DH / 32, NEXP), tb, 0, stream>>>(W1, Wt1, DH, DMOE);
  k_transpose_cvt<<<dim3(DH / 32, DMOE / 32, NEXP), tb, 0, stream>>>(W2, Wt2, DMOE, DH);
  k_transpose_cvt<<<dim3(DH / 32, DH / 32, 1), tb, 0, stream>>>(W_out, WtOut, DH, DH);
  k_cvt_bf16<<<(NTOK * DIN / 4 + 255) / 256, 256, 0, stream>>>(x, xbf, NTOK * DIN / 4);

  k_gate_prep<<<64, 256, 0, stream>>>(W_in, W_gate, b_in, b_gate, G, cvec);
  k_gating<<<NTOK / 4, 256, 0, stream>>>(x, G, cvec, cnt, list, wlist);
  k_scan<<<1, 64, 0, stream>>>(cnt, offs);

  // h = x @ W_in + b_in  (bf16 out)
  k_gemm<0><<<dim3(DH / 128, NTOK / 128, 1), 256, 0, stream>>>(
      xbf, WtIn, b_in, hbf, NTOK, DH, DIN, nullptr, nullptr, nullptr, nullptr);
  // mid = relu(h_gathered @ W1[e] + b1[e])
  k_gemm<1><<<dim3(DMOE / 128, NTOK / 128, NEXP), 256, 0, stream>>>(
      hbf, Wt1, b1, mid, NTOK, DMOE, DH, cnt, offs, list, wlist);
  // eout[t][slot] = (mid @ W2[e] + b2[e]) * route_w
  k_gemm<2><<<dim3(DH / 128, NTOK / 128, NEXP), 256, 0, stream>>>(
      mid, Wt2, b2, eout, NTOK, DH, DMOE, cnt, offs, list, wlist);
  k_combine<<<NTOK * DH / 4 / 256, 256, 0, stream>>>(eout, moebf);
  // out = moe @ W_out + b_out (fp32 out)
  k_gemm<3><<<dim3(DH / 128, NTOK / 128, 1), 256, 0, stream>>>(
      moebf, WtOut, b_out, (float*)d_out, NTOK, DH, DH, nullptr, nullptr, nullptr, nullptr);
}

// Round 2
// 577.979 us; speedup vs baseline: 1.0726x; 1.0726x over previous
//
#include <hip/hip_runtime.h>
#include <hip/hip_bf16.h>

typedef __bf16 bf16_t;
typedef bf16_t bf16x8 __attribute__((ext_vector_type(8)));
typedef bf16_t bf16x4 __attribute__((ext_vector_type(4)));
typedef float f32x4 __attribute__((ext_vector_type(4)));

#define DIN 1024
#define DH 1024
#define DMOE 4096
#define NEXP 8
#define NTOK 4096

__device__ __forceinline__ void gload_lds16(const bf16_t* g, bf16_t* l) {
  __builtin_amdgcn_global_load_lds(
      (const __attribute__((address_space(1))) void*)g,
      (__attribute__((address_space(3))) void*)l, 16, 0, 0);
}

// ---------------- small utility kernels ----------------

__global__ void k_zero8(int* p) {
  if (threadIdx.x < 8) p[threadIdx.x] = 0;
}

// src [b][R][C] f32 -> dst [b][C][R] bf16
__global__ void k_transpose_cvt(const float* __restrict__ src, bf16_t* __restrict__ dst,
                                int R, int C) {
  __shared__ float tile[32][33];
  const size_t mofs = (size_t)blockIdx.z * R * C;
  const float* s = src + mofs;
  bf16_t* d = dst + mofs;
  const int c0 = blockIdx.x * 32, r0 = blockIdx.y * 32;
  const int tx = threadIdx.x, ty = threadIdx.y;
#pragma unroll
  for (int i = 0; i < 32; i += 8)
    tile[ty + i][tx] = s[(size_t)(r0 + ty + i) * C + (c0 + tx)];
  __syncthreads();
#pragma unroll
  for (int i = 0; i < 32; i += 8)
    d[(size_t)(c0 + ty + i) * R + (r0 + tx)] = (bf16_t)tile[tx][ty + i];
}

__global__ void k_cvt_bf16(const float* __restrict__ src, bf16_t* __restrict__ dst, int n4) {
  const int i = blockIdx.x * blockDim.x + threadIdx.x;
  if (i < n4) {
    const float4 v = *(const float4*)(src + (size_t)i * 4);
    bf16x4 o;
    o.x = (bf16_t)v.x; o.y = (bf16_t)v.y; o.z = (bf16_t)v.z; o.w = (bf16_t)v.w;
    *(bf16x4*)(dst + (size_t)i * 4) = o;
  }
}

// G[d][e] = sum_k W_in[d][k] * W_gate[k][e]  (fp64); row d==DH computes c[e] from b_in
__global__ void k_gate_prep(const float* __restrict__ Win, const float* __restrict__ Wgate,
                            const float* __restrict__ b_in, const float* __restrict__ b_gate,
                            double* __restrict__ G, double* __restrict__ cvec) {
  const int lane = threadIdx.x & 63;
  const int wave = (blockIdx.x * blockDim.x + threadIdx.x) >> 6;
  const int nw = (gridDim.x * blockDim.x) >> 6;
  for (int d = wave; d <= DIN; d += nw) {
    const float* row = (d < DIN) ? (Win + (size_t)d * DH) : b_in;
    double acc[8] = {0, 0, 0, 0, 0, 0, 0, 0};
    for (int k = lane; k < DH; k += 64) {
      const double xv = (double)row[k];
      const float* g = Wgate + (size_t)k * NEXP;
#pragma unroll
      for (int ee = 0; ee < 8; ++ee) acc[ee] += xv * (double)g[ee];
    }
#pragma unroll
    for (int ee = 0; ee < 8; ++ee) {
      double a = acc[ee];
      for (int o = 32; o > 0; o >>= 1) a += __shfl_down(a, o);
      acc[ee] = a;
    }
    if (lane == 0) {
      if (d < DIN) {
#pragma unroll
        for (int ee = 0; ee < 8; ++ee) G[(size_t)d * 8 + ee] = acc[ee];
      } else {
#pragma unroll
        for (int ee = 0; ee < 8; ++ee) cvec[ee] = acc[ee] + (double)b_gate[ee];
      }
    }
  }
}

// per token: fp64 logits via fused G, softmax, top-2, scatter into expert lists
__global__ void k_gating(const float* __restrict__ x, const double* __restrict__ G,
                         const double* __restrict__ cvec, int* __restrict__ cnt,
                         int* __restrict__ list, float* __restrict__ wlist) {
  const int lane = threadIdx.x & 63;
  const int t = blockIdx.x * (blockDim.x >> 6) + (threadIdx.x >> 6);
  if (t >= NTOK) return;
  const float* xr = x + (size_t)t * DIN;
  double acc[8] = {0, 0, 0, 0, 0, 0, 0, 0};
  for (int d = lane; d < DIN; d += 64) {
    const double xv = (double)xr[d];
    const double* g = G + (size_t)d * 8;
#pragma unroll
    for (int ee = 0; ee < 8; ++ee) acc[ee] += xv * g[ee];
  }
#pragma unroll
  for (int ee = 0; ee < 8; ++ee) {
    double a = acc[ee];
    for (int o = 32; o > 0; o >>= 1) a += __shfl_down(a, o);
    acc[ee] = a;
  }
  if (lane == 0) {
    double l[8];
#pragma unroll
    for (int ee = 0; ee < 8; ++ee) l[ee] = acc[ee] + cvec[ee];
    double m = l[0];
#pragma unroll
    for (int ee = 1; ee < 8; ++ee) m = fmax(m, l[ee]);
    double p[8];
#pragma unroll
    for (int ee = 0; ee < 8; ++ee) p[ee] = exp(l[ee] - m);
    int i1 = 0;
#pragma unroll
    for (int ee = 1; ee < 8; ++ee)
      if (p[ee] > p[i1]) i1 = ee;
    int i2 = (i1 == 0) ? 1 : 0;
#pragma unroll
    for (int ee = 0; ee < 8; ++ee)
      if (ee != i1 && p[ee] > p[i2]) i2 = ee;
    const double s2 = p[i1] + p[i2];
    const float w1 = (float)(p[i1] / s2);
    const float w2 = (float)(p[i2] / s2);
    int lp = atomicAdd(&cnt[i1], 1);
    list[i1 * NTOK + lp] = t * 2;
    wlist[i1 * NTOK + lp] = w1;
    lp = atomicAdd(&cnt[i2], 1);
    list[i2 * NTOK + lp] = t * 2 + 1;
    wlist[i2 * NTOK + lp] = w2;
  }
}

__global__ void k_scan(const int* __restrict__ cnt, int* __restrict__ offs) {
  if (threadIdx.x == 0) {
    int s = 0;
    for (int e = 0; e < NEXP; ++e) { offs[e] = s; s += cnt[e]; }
    offs[NEXP] = s;
  }
}

// moe_bf16[t] = bf16(eout[t][0] + eout[t][1])   (route weights already applied)
__global__ void k_combine(const float* __restrict__ eout, bf16_t* __restrict__ moebf) {
  const int i = blockIdx.x * blockDim.x + threadIdx.x;
  const int t = i >> 8;
  const int q = (i & 255) * 4;
  const float4 a = *(const float4*)(eout + ((size_t)t * 2) * DH + q);
  const float4 b = *(const float4*)(eout + ((size_t)t * 2 + 1) * DH + q);
  bf16x4 o;
  o.x = (bf16_t)(a.x + b.x); o.y = (bf16_t)(a.y + b.y);
  o.z = (bf16_t)(a.z + b.z); o.w = (bf16_t)(a.w + b.w);
  *(bf16x4*)(moebf + (size_t)t * DH + q) = o;
}

// ---------------- 128x128 BK=32 bf16 MFMA GEMM, 4 waves ----------------
// Pipelined: 3 LDS buffers, depth-2 prefetch via global_load_lds, raw s_barrier +
// counted vmcnt (T3/T4-minimum). 4 gload_lds per wave per K-tile.
// MODE 0: plain, bf16 out (h)
// MODE 1: expert, A rows gathered via list (token = entry>>1), relu, bf16 out at rowOff+r
// MODE 2: expert, A = mid + rowOff, out fp32 scattered to eout[entry][*] scaled by wlist
// MODE 3: plain, fp32 out (final)
template <int MODE>
__global__ __launch_bounds__(256, 3) void k_gemm(
    const bf16_t* __restrict__ Abase, const bf16_t* __restrict__ Bbase,
    const float* __restrict__ biasBase, void* __restrict__ Cbase,
    int M, int N, int K,
    const int* __restrict__ cnt, const int* __restrict__ offs,
    const int* __restrict__ listBase, const float* __restrict__ wlistBase) {
  const int e = blockIdx.z;
  const int mblk = blockIdx.y, nblk = blockIdx.x;
  int Mloc = M;
  const bf16_t* A = Abase;
  const bf16_t* B = Bbase;
  const float* bias = biasBase;
  const int* myList = nullptr;
  const float* myW = nullptr;
  int rowOff = 0;
  if constexpr (MODE == 1 || MODE == 2) {
    Mloc = cnt[e];
    if (mblk * 128 >= Mloc) return;  // uniform early exit, before any barrier
    B = Bbase + (size_t)e * N * K;
    bias = biasBase + (size_t)e * N;
    myList = listBase + e * NTOK;
    myW = wlistBase + e * NTOK;
    rowOff = offs[e];
    if constexpr (MODE == 2) A = Abase + (size_t)rowOff * K;
  }

  __shared__ bf16_t As[3][128 * 32];
  __shared__ bf16_t Bs[3][128 * 32];

  const int tid = threadIdx.x;
  const int lane = tid & 63;
  const int wid = tid >> 6;
  const int wr = wid >> 1, wc = wid & 1;

  // staging: each wave stages rows [wid*32, wid*32+32) of A and of Bt, 16B/lane
  const int srow0 = wid * 32 + (lane >> 2);
  const int srow1 = srow0 + 16;
  const int skcol = (lane & 3) * 8;

  int ar0 = mblk * 128 + srow0;
  int ar1 = mblk * 128 + srow1;
  if constexpr (MODE == 1 || MODE == 2) {
    if (ar0 > Mloc - 1) ar0 = Mloc - 1;
    if (ar1 > Mloc - 1) ar1 = Mloc - 1;
  }
  size_t arow0 = (size_t)ar0, arow1 = (size_t)ar1;
  if constexpr (MODE == 1) {
    arow0 = (size_t)(myList[ar0] >> 1);
    arow1 = (size_t)(myList[ar1] >> 1);
  }
  const bf16_t* aptr0 = A + arow0 * K + skcol;
  const bf16_t* aptr1 = A + arow1 * K + skcol;
  const bf16_t* bptr0 = B + (size_t)(nblk * 128 + srow0) * K + skcol;
  const bf16_t* bptr1 = B + (size_t)(nblk * 128 + srow1) * K + skcol;

  const int ldsOfsA0 = (wid * 32) * 32;        // wave-uniform LDS offsets
  const int ldsOfsA1 = (wid * 32 + 16) * 32;

  f32x4 acc[4][4] = {};

  const int nkt = K >> 5;

  auto stage = [&](int buf, int kt) {
    const size_t ko = (size_t)kt * 32;
    gload_lds16(aptr0 + ko, &As[buf][ldsOfsA0]);
    gload_lds16(aptr1 + ko, &As[buf][ldsOfsA1]);
    gload_lds16(bptr0 + ko, &Bs[buf][ldsOfsA0]);
    gload_lds16(bptr1 + ko, &Bs[buf][ldsOfsA1]);
  };

  // prologue: prefetch tiles 0 and 1
  stage(0, 0);
  if (nkt > 1) stage(1, 1);

  int cur = 0;
  for (int kt = 0; kt < nkt; ++kt) {
    // issue tile kt+2 into the buffer whose last reads finished at iter kt-1
    int nxt = cur + 2;
    if (nxt >= 3) nxt -= 3;
    if (kt + 2 < nkt) {
      stage(nxt, kt + 2);
      asm volatile("s_waitcnt vmcnt(8)" ::: "memory");  // tile kt's 4 loads landed
    } else if (kt + 1 < nkt) {
      asm volatile("s_waitcnt vmcnt(4)" ::: "memory");
    } else {
      asm volatile("s_waitcnt vmcnt(0)" ::: "memory");
    }
    __builtin_amdgcn_s_barrier();  // all waves' tile-kt LDS writes visible

    const int fr = lane & 15;
    const int kq = (lane >> 4) * 8;
    bf16x8 af[4], bfr[4];
#pragma unroll
    for (int m = 0; m < 4; ++m)
      af[m] = *(const bf16x8*)&As[cur][(wr * 64 + m * 16 + fr) * 32 + kq];
#pragma unroll
    for (int n = 0; n < 4; ++n)
      bfr[n] = *(const bf16x8*)&Bs[cur][(wc * 64 + n * 16 + fr) * 32 + kq];
#pragma unroll
    for (int m = 0; m < 4; ++m)
#pragma unroll
      for (int n = 0; n < 4; ++n)
        acc[m][n] = __builtin_amdgcn_mfma_f32_16x16x32_bf16(af[m], bfr[n], acc[m][n], 0, 0, 0);

    __builtin_amdgcn_s_barrier();  // all reads of buf[cur] done before it is restaged
    cur += 1;
    if (cur >= 3) cur -= 3;
  }

  // epilogue: C row = (lane>>4)*4 + j (+16m), col = lane&15 (+16n)  [m89-verified]
  const int colBase = nblk * 128 + wc * 64 + (lane & 15);
  const int rowBase = mblk * 128 + wr * 64 + ((lane >> 4) << 2);
#pragma unroll
  for (int n = 0; n < 4; ++n) {
    const int c = colBase + n * 16;
    const float bv = bias[c];
#pragma unroll
    for (int m = 0; m < 4; ++m) {
#pragma unroll
      for (int j = 0; j < 4; ++j) {
        const int r = rowBase + m * 16 + j;
        float v = acc[m][n][j] + bv;
        if constexpr (MODE == 0) {
          ((bf16_t*)Cbase)[(size_t)r * N + c] = (bf16_t)v;
        } else if constexpr (MODE == 1) {
          if (r < Mloc) {
            v = fmaxf(v, 0.0f);
            ((bf16_t*)Cbase)[(size_t)(rowOff + r) * N + c] = (bf16_t)v;
          }
        } else if constexpr (MODE == 2) {
          if (r < Mloc) {
            const int entry = myList[r];
            const float w = myW[r];
            ((float*)Cbase)[(size_t)entry * DH + c] = v * w;
          }
        } else {
          ((float*)Cbase)[(size_t)r * N + c] = v;
        }
      }
    }
  }
}

// ---------------- launch ----------------

extern "C" void kernel_launch(void* const* d_in, const int* in_sizes, int n_in,
                              void* d_out, int out_size, void* d_ws, size_t ws_size,
                              hipStream_t stream) {
  const float* x      = (const float*)d_in[0];
  const float* W_in   = (const float*)d_in[1];
  const float* b_in   = (const float*)d_in[2];
  const float* W_gate = (const float*)d_in[3];
  const float* b_gate = (const float*)d_in[4];
  const float* W1     = (const float*)d_in[5];
  const float* b1     = (const float*)d_in[6];
  const float* W2     = (const float*)d_in[7];
  const float* b2     = (const float*)d_in[8];
  const float* W_out  = (const float*)d_in[9];
  const float* b_out  = (const float*)d_in[10];

  char* ws = (char*)d_ws;
  size_t off = 0;
  auto alloc = [&](size_t bytes) -> void* {
    void* p = ws + off;
    off += (bytes + 255) & ~(size_t)255;
    return p;
  };

  bf16_t* WtIn  = (bf16_t*)alloc((size_t)DH * DIN * 2);          // [DH][DIN]
  bf16_t* Wt1   = (bf16_t*)alloc((size_t)NEXP * DMOE * DH * 2);  // [E][DMOE][DH]
  bf16_t* Wt2   = (bf16_t*)alloc((size_t)NEXP * DH * DMOE * 2);  // [E][DH][DMOE]
  bf16_t* WtOut = (bf16_t*)alloc((size_t)DH * DH * 2);           // [DOUT][DH]
  bf16_t* xbf   = (bf16_t*)alloc((size_t)NTOK * DIN * 2);
  bf16_t* hbf   = (bf16_t*)alloc((size_t)NTOK * DH * 2);
  bf16_t* mid   = (bf16_t*)alloc((size_t)2 * NTOK * DMOE * 2);   // [2N][DMOE]
  float*  eout  = (float*)alloc((size_t)2 * NTOK * DH * 4);      // [2N][DH] (t*2+slot)
  bf16_t* moebf = (bf16_t*)alloc((size_t)NTOK * DH * 2);
  double* G     = (double*)alloc((size_t)DIN * 8 * 8);
  double* cvec  = (double*)alloc(8 * 8);
  int*    cnt   = (int*)alloc(NEXP * 4);
  int*    offs  = (int*)alloc((NEXP + 1) * 4);
  int*    list  = (int*)alloc((size_t)NEXP * NTOK * 4);
  float*  wlist = (float*)alloc((size_t)NEXP * NTOK * 4);

  k_zero8<<<1, 64, 0, stream>>>(cnt);

  dim3 tb(32, 8, 1);
  k_transpose_cvt<<<dim3(DH / 32, DIN / 32, 1), tb, 0, stream>>>(W_in, WtIn, DIN, DH);
  k_transpose_cvt<<<dim3(DMOE / 32, DH / 32, NEXP), tb, 0, stream>>>(W1, Wt1, DH, DMOE);
  k_transpose_cvt<<<dim3(DH / 32, DMOE / 32, NEXP), tb, 0, stream>>>(W2, Wt2, DMOE, DH);
  k_transpose_cvt<<<dim3(DH / 32, DH / 32, 1), tb, 0, stream>>>(W_out, WtOut, DH, DH);
  k_cvt_bf16<<<(NTOK * DIN / 4 + 255) / 256, 256, 0, stream>>>(x, xbf, NTOK * DIN / 4);

  k_gate_prep<<<64, 256, 0, stream>>>(W_in, W_gate, b_in, b_gate, G, cvec);
  k_gating<<<NTOK / 4, 256, 0, stream>>>(x, G, cvec, cnt, list, wlist);
  k_scan<<<1, 64, 0, stream>>>(cnt, offs);

  // h = x @ W_in + b_in  (bf16 out)
  k_gemm<0><<<dim3(DH / 128, NTOK / 128, 1), 256, 0, stream>>>(
      xbf, WtIn, b_in, hbf, NTOK, DH, DIN, nullptr, nullptr, nullptr, nullptr);
  // mid = relu(h_gathered @ W1[e] + b1[e])
  k_gemm<1><<<dim3(DMOE / 128, NTOK / 128, NEXP), 256, 0, stream>>>(
      hbf, Wt1, b1, mid, NTOK, DMOE, DH, cnt, offs, list, wlist);
  // eout[t][slot] = (mid @ W2[e] + b2[e]) * route_w
  k_gemm<2><<<dim3(DH / 128, NTOK / 128, NEXP), 256, 0, stream>>>(
      mid, Wt2, b2, eout, NTOK, DH, DMOE, cnt, offs, list, wlist);
  k_combine<<<NTOK * DH / 4 / 256, 256, 0, stream>>>(eout, moebf);
  // out = moe @ W_out + b_out (fp32 out)
  k_gemm<3><<<dim3(DH / 128, NTOK / 128, 1), 256, 0, stream>>>(
      moebf, WtOut, b_out, (float*)d_out, NTOK, DH, DH, nullptr, nullptr, nullptr, nullptr);
}